// Round 10
// baseline (1549.342 us; speedup 1.0000x reference)
//
#include <hip/hip_runtime.h>

#define DIM 128
#define NB 64   // dst nodes per aggregation block (LDS tile = NB*DIM*4 = 32 KB)
typedef unsigned int uint;
typedef unsigned short ushort;

// bf16 pack (RNE)
__device__ __forceinline__ ushort f2bf(float x) {
    uint u = __float_as_uint(x);
    u = u + 0x7FFFu + ((u >> 16) & 1u);
    return (ushort)(u >> 16);
}
__device__ __forceinline__ uint pack2(float a, float b) {
    return (uint)f2bf(a) | ((uint)f2bf(b) << 16);
}

// ---------------- degree count ----------------
__global__ __launch_bounds__(256) void k_count(const int* __restrict__ dst,
                                               int* __restrict__ deg, int E) {
    int t = blockIdx.x * 256 + threadIdx.x;
    if (t < E) atomicAdd(&deg[dst[t]], 1);
}

__global__ __launch_bounds__(256) void k_dinv(const int* __restrict__ deg,
                                              float* __restrict__ dinv, int N) {
    int t = blockIdx.x * 256 + threadIdx.x;
    if (t < N) dinv[t] = rsqrtf((float)(deg[t] + 1));  // +1 = self-loop
}

// ---------------- parallel exclusive scan: blockwise -> seg -> add ----------------
__global__ __launch_bounds__(256) void k_scanA(const int* __restrict__ deg,
                                               int* __restrict__ rowptr,
                                               int* __restrict__ segsum, int N) {
    int i = blockIdx.x * 256 + threadIdx.x;
    int v = (i < N) ? deg[i] : 0;
    __shared__ int ps[256];
    ps[threadIdx.x] = v;
    __syncthreads();
    for (int off = 1; off < 256; off <<= 1) {
        int u = (threadIdx.x >= off) ? ps[threadIdx.x - off] : 0;
        __syncthreads();
        ps[threadIdx.x] += u;
        __syncthreads();
    }
    if (i < N) rowptr[i] = ps[threadIdx.x] - v;   // exclusive within block
    if (threadIdx.x == 255) segsum[blockIdx.x] = ps[255];
}

__global__ __launch_bounds__(256) void k_scanB(int* __restrict__ segsum, int nseg) {
    int t = threadIdx.x;
    int v = (t < nseg) ? segsum[t] : 0;
    __shared__ int ps[256];
    ps[t] = v;
    __syncthreads();
    for (int off = 1; off < 256; off <<= 1) {
        int u = (t >= off) ? ps[t - off] : 0;
        __syncthreads();
        ps[t] += u;
        __syncthreads();
    }
    if (t < nseg) segsum[t] = ps[t] - v;
}

__global__ __launch_bounds__(256) void k_scanC(int* __restrict__ rowptr,
                                               const int* __restrict__ segsum,
                                               int* __restrict__ cursor, int N, int E) {
    int i = blockIdx.x * 256 + threadIdx.x;
    if (i < N) {
        int r = rowptr[i] + segsum[blockIdx.x];
        rowptr[i] = r;
        cursor[i] = r;
    }
    if (i == 0) rowptr[N] = E;
}

// ---------------- CSR fill: {src|dloc<<16, weight} per edge, grouped by dst --------
// Requires N <= 65536 (src fits 16 bits); dloc = dst & (NB-1) fits 6 bits.
__global__ __launch_bounds__(256) void k_fill(const int* __restrict__ src,
                                              const int* __restrict__ dst,
                                              const float* __restrict__ dinv,
                                              int* __restrict__ cursor,
                                              int2* __restrict__ csr, int E) {
    int e = blockIdx.x * 256 + threadIdx.x;
    if (e >= E) return;
    int s = src[e], d = dst[e];
    int p = atomicAdd(&cursor[d], 1);
    float w = dinv[s] * dinv[d];
    uint pk = (uint)s | ((uint)(d & (NB - 1)) << 16);
    csr[p] = make_int2((int)pk, __float_as_int(w));
}

// ---------------- dense GEMM: H(bf16) = (cvec +) f(X) @ W ----------------
template<bool RELU_IN, bool ADD_C>
__global__ __launch_bounds__(256) void k_gemm(const float* __restrict__ X,
                                              const float* __restrict__ W,
                                              const float* __restrict__ Cvec,
                                              ushort* __restrict__ H, int n) {
    __shared__ float sW[64 * DIM];   // 32 KB, one K-chunk of W [k2][j]
    __shared__ float sX[32][DIM];    // 16 KB
    const int jq = threadIdx.x & 31;
    const int rr = threadIdx.x >> 5;   // 0..7
    float4 cj = ADD_C ? ((const float4*)Cvec)[jq] : make_float4(0.f, 0.f, 0.f, 0.f);
    for (int base = blockIdx.x * 32; base < n; base += gridDim.x * 32) {
        __syncthreads();
        for (int u = threadIdx.x; u < 32 * 32; u += 256) {
            int row = u >> 5, c4 = u & 31;
            int gi = base + row;
            float4 v = make_float4(0.f, 0.f, 0.f, 0.f);
            if (gi < n) v = ((const float4*)(X + (size_t)gi * DIM))[c4];
            if (RELU_IN) {
                v.x = fmaxf(v.x, 0.f); v.y = fmaxf(v.y, 0.f);
                v.z = fmaxf(v.z, 0.f); v.w = fmaxf(v.w, 0.f);
            }
            ((float4*)sX[row])[c4] = v;
        }
        float4 a0 = cj, a1 = cj, a2 = cj, a3 = cj;
        for (int kk = 0; kk < DIM; kk += 64) {
            __syncthreads();
            for (int u = threadIdx.x; u < 64 * 32; u += 256)
                ((float4*)sW)[u] = ((const float4*)(W + (size_t)kk * DIM))[u];
            __syncthreads();
            #pragma unroll 8
            for (int k2 = 0; k2 < 64; ++k2) {
                int k = kk + k2;
                float4 w4 = ((const float4*)sW)[k2 * 32 + jq];
                float x0 = sX[rr * 4 + 0][k], x1 = sX[rr * 4 + 1][k];
                float x2 = sX[rr * 4 + 2][k], x3 = sX[rr * 4 + 3][k];
                a0.x = fmaf(x0, w4.x, a0.x); a0.y = fmaf(x0, w4.y, a0.y);
                a0.z = fmaf(x0, w4.z, a0.z); a0.w = fmaf(x0, w4.w, a0.w);
                a1.x = fmaf(x1, w4.x, a1.x); a1.y = fmaf(x1, w4.y, a1.y);
                a1.z = fmaf(x1, w4.z, a1.z); a1.w = fmaf(x1, w4.w, a1.w);
                a2.x = fmaf(x2, w4.x, a2.x); a2.y = fmaf(x2, w4.y, a2.y);
                a2.z = fmaf(x2, w4.z, a2.z); a2.w = fmaf(x2, w4.w, a2.w);
                a3.x = fmaf(x3, w4.x, a3.x); a3.y = fmaf(x3, w4.y, a3.y);
                a3.z = fmaf(x3, w4.z, a3.z); a3.w = fmaf(x3, w4.w, a3.w);
            }
        }
        int i0 = base + rr * 4;
        if (i0 + 0 < n) ((uint2*)(H + (size_t)(i0 + 0) * DIM))[jq] =
            make_uint2(pack2(a0.x, a0.y), pack2(a0.z, a0.w));
        if (i0 + 1 < n) ((uint2*)(H + (size_t)(i0 + 1) * DIM))[jq] =
            make_uint2(pack2(a1.x, a1.y), pack2(a1.z, a1.w));
        if (i0 + 2 < n) ((uint2*)(H + (size_t)(i0 + 2) * DIM))[jq] =
            make_uint2(pack2(a2.x, a2.y), pack2(a2.z, a2.w));
        if (i0 + 3 < n) ((uint2*)(H + (size_t)(i0 + 3) * DIM))[jq] =
            make_uint2(pack2(a3.x, a3.y), pack2(a3.z, a3.w));
    }
}

// ---------------- c[j] = sum_k relu(posts[root][k]) * W2[k][j] ----------------
__global__ __launch_bounds__(DIM) void k_cvec(const float* __restrict__ posts,
                                              const int* __restrict__ root,
                                              const float* __restrict__ W2,
                                              float* __restrict__ cvec) {
    int j = threadIdx.x;
    const float* xr = posts + (size_t)root[0] * DIM;
    float acc = 0.0f;
    #pragma unroll 8
    for (int k = 0; k < DIM; ++k)
        acc = fmaf(fmaxf(xr[k], 0.0f), W2[k * DIM + j], acc);
    cvec[j] = acc;
}

// ---------------- edge-parallel aggregation over a 64-dst-node LDS tile ----------
// Block owns dst nodes [b0, b0+NB); 8 groups of 32 lanes take edges of the block's
// contiguous CSR span round-robin (2-deep unrolled -> independent gathers in
// flight per group). Rows accumulate via LDS f32 atomics. Finalize fuses
// self-loop + bias (+ relu + column-sum for layer 2).
template<bool L2>
__global__ __launch_bounds__(256, 4) void k_agg(const int2* __restrict__ csr,
                                                const int* __restrict__ rowptr,
                                                const float* __restrict__ dinv,
                                                const ushort* __restrict__ h,
                                                const float* __restrict__ bias,
                                                const int* __restrict__ root,
                                                float* __restrict__ conv1,
                                                float* __restrict__ meanacc,
                                                float* __restrict__ out, int N) {
    __shared__ float acc[NB * DIM];   // 32 KB
    const int tid = threadIdx.x;
    const int gid = tid >> 5;   // 0..7
    const int q   = tid & 31;
    const int b0 = blockIdx.x * NB;
    const int b1 = min(b0 + NB, N);

    #pragma unroll
    for (int u = 0; u < NB * DIM / 4 / 256; ++u)
        ((float4*)acc)[tid + u * 256] = make_float4(0.f, 0.f, 0.f, 0.f);
    __syncthreads();

    const int beg = rowptr[b0], end = rowptr[b1];
    int e = beg + gid;
    for (; e + 8 < end; e += 16) {
        int2 c0 = csr[e], c1 = csr[e + 8];
        float w0 = __int_as_float(c0.y), w1 = __int_as_float(c1.y);
        uint p0 = (uint)c0.x, p1 = (uint)c1.x;
        uint2 v0 = ((const uint2*)(h + (size_t)(p0 & 0xFFFFu) * DIM))[q];
        uint2 v1 = ((const uint2*)(h + (size_t)(p1 & 0xFFFFu) * DIM))[q];
        float* r0 = acc + ((p0 >> 16) & (NB - 1)) * DIM + q * 4;
        float* r1 = acc + ((p1 >> 16) & (NB - 1)) * DIM + q * 4;
        atomicAdd(r0 + 0, __uint_as_float(v0.x << 16) * w0);
        atomicAdd(r0 + 1, __uint_as_float(v0.x & 0xFFFF0000u) * w0);
        atomicAdd(r0 + 2, __uint_as_float(v0.y << 16) * w0);
        atomicAdd(r0 + 3, __uint_as_float(v0.y & 0xFFFF0000u) * w0);
        atomicAdd(r1 + 0, __uint_as_float(v1.x << 16) * w1);
        atomicAdd(r1 + 1, __uint_as_float(v1.x & 0xFFFF0000u) * w1);
        atomicAdd(r1 + 2, __uint_as_float(v1.y << 16) * w1);
        atomicAdd(r1 + 3, __uint_as_float(v1.y & 0xFFFF0000u) * w1);
    }
    if (e < end) {
        int2 c0 = csr[e];
        float w0 = __int_as_float(c0.y);
        uint p0 = (uint)c0.x;
        uint2 v0 = ((const uint2*)(h + (size_t)(p0 & 0xFFFFu) * DIM))[q];
        float* r0 = acc + ((p0 >> 16) & (NB - 1)) * DIM + q * 4;
        atomicAdd(r0 + 0, __uint_as_float(v0.x << 16) * w0);
        atomicAdd(r0 + 1, __uint_as_float(v0.x & 0xFFFF0000u) * w0);
        atomicAdd(r0 + 2, __uint_as_float(v0.y << 16) * w0);
        atomicAdd(r0 + 3, __uint_as_float(v0.y & 0xFFFF0000u) * w0);
    }
    __syncthreads();

    float4 bv = ((const float4*)bias)[q];
    if (!L2) {
        int rt = root[0];
        for (int l = gid; l < b1 - b0; l += 8) {
            int d = b0 + l;
            float di = dinv[d], sl = di * di;
            uint2 hv = ((const uint2*)(h + (size_t)d * DIM))[q];
            float4 a = ((const float4*)(acc + l * DIM))[q];
            float4 r;
            r.x = fmaf(__uint_as_float(hv.x << 16), sl, a.x) + bv.x;
            r.y = fmaf(__uint_as_float(hv.x & 0xFFFF0000u), sl, a.y) + bv.y;
            r.z = fmaf(__uint_as_float(hv.y << 16), sl, a.z) + bv.z;
            r.w = fmaf(__uint_as_float(hv.y & 0xFFFF0000u), sl, a.w) + bv.w;
            ((float4*)(conv1 + (size_t)d * DIM))[q] = r;
            if (d == rt) ((float4*)out)[q] = r;   // conv1_root (no relu)
        }
    } else {
        float4 s4 = make_float4(0.f, 0.f, 0.f, 0.f);
        for (int l = gid; l < b1 - b0; l += 8) {
            int d = b0 + l;
            float di = dinv[d], sl = di * di;
            uint2 hv = ((const uint2*)(h + (size_t)d * DIM))[q];
            float4 a = ((const float4*)(acc + l * DIM))[q];
            s4.x += fmaxf(fmaf(__uint_as_float(hv.x << 16), sl, a.x) + bv.x, 0.f);
            s4.y += fmaxf(fmaf(__uint_as_float(hv.x & 0xFFFF0000u), sl, a.y) + bv.y, 0.f);
            s4.z += fmaxf(fmaf(__uint_as_float(hv.y << 16), sl, a.z) + bv.z, 0.f);
            s4.w += fmaxf(fmaf(__uint_as_float(hv.y & 0xFFFF0000u), sl, a.w) + bv.w, 0.f);
        }
        __syncthreads();                 // done reading acc
        ((float4*)acc)[tid] = s4;        // reuse acc for reduction
        __syncthreads();
        if (tid < 32) {
            float4 s = ((float4*)acc)[tid];
            #pragma unroll
            for (int g = 1; g < 8; ++g) {
                float4 o = ((float4*)acc)[g * 32 + tid];
                s.x += o.x; s.y += o.y; s.z += o.z; s.w += o.w;
            }
            unsafeAtomicAdd(&meanacc[tid * 4 + 0], s.x);
            unsafeAtomicAdd(&meanacc[tid * 4 + 1], s.y);
            unsafeAtomicAdd(&meanacc[tid * 4 + 2], s.z);
            unsafeAtomicAdd(&meanacc[tid * 4 + 3], s.w);
        }
    }
}

__global__ __launch_bounds__(DIM) void k_reduce(const float* __restrict__ meanacc,
                                                float* __restrict__ out, int N) {
    int j = threadIdx.x;
    out[DIM + j] = meanacc[j] / (float)N;
}

extern "C" void kernel_launch(void* const* d_in, const int* in_sizes, int n_in,
                              void* d_out, int out_size, void* d_ws, size_t ws_size,
                              hipStream_t stream) {
    const float* posts = (const float*)d_in[0];
    const int*   eidx  = (const int*)d_in[1];
    const int*   root  = (const int*)d_in[2];
    const float* W1    = (const float*)d_in[3];
    const float* b1    = (const float*)d_in[4];
    const float* W2    = (const float*)d_in[5];
    const float* b2    = (const float*)d_in[6];
    float* out = (float*)d_out;

    int N = in_sizes[0] / DIM;
    int E = in_sizes[1] / 2;
    const int* src = eidx;
    const int* dst = eidx + E;
    int nseg = (N + 255) / 256;   // 196 for N=50000 (fits k_scanB's 256)
    int nblk = (N + NB - 1) / NB; // 782 aggregation blocks

    char* ws = (char*)d_ws;
    size_t off = 0;
    auto alloc = [&](size_t bytes) {
        void* p = ws + off;
        off += (bytes + 511) & ~(size_t)511;
        return p;
    };
    int*    deg     = (int*)   alloc((size_t)N * 4);
    int*    rowptr  = (int*)   alloc((size_t)(N + 1) * 4);
    int*    cursor  = (int*)   alloc((size_t)N * 4);
    int*    segsum  = (int*)   alloc((size_t)nseg * 4);
    float*  dinv    = (float*) alloc((size_t)N * 4);
    float*  cvec    = (float*) alloc(DIM * 4);
    float*  meanacc = (float*) alloc(DIM * 4);
    int2*   csr     = (int2*)  alloc((size_t)E * 8);
    ushort* h       = (ushort*)alloc((size_t)N * DIM * 2);   // bf16 h1, then h2
    float*  conv1   = (float*) alloc((size_t)N * DIM * 4);   // conv1_out (f32)

    hipMemsetAsync(deg, 0, (size_t)N * 4, stream);
    hipMemsetAsync(meanacc, 0, DIM * 4, stream);

    // CSR build (once, shared by both layers); parallel 3-stage scan
    k_count<<<(E + 255) / 256, 256, 0, stream>>>(dst, deg, E);
    k_scanA<<<nseg, 256, 0, stream>>>(deg, rowptr, segsum, N);
    k_scanB<<<1, 256, 0, stream>>>(segsum, nseg);
    k_scanC<<<nseg, 256, 0, stream>>>(rowptr, segsum, cursor, N, E);
    k_dinv<<<(N + 255) / 256, 256, 0, stream>>>(deg, dinv, N);
    k_fill<<<(E + 255) / 256, 256, 0, stream>>>(src, dst, dinv, cursor, csr, E);

    // layer 1
    k_gemm<false, false><<<512, 256, 0, stream>>>(posts, W1, nullptr, h, N);
    k_agg<false><<<nblk, 256, 0, stream>>>(csr, rowptr, dinv, h, b1, root,
                                           conv1, meanacc, out, N);

    // layer 2: h2 = cvec + relu(conv1) @ W2[128:], cvec = relu(post_root) @ W2[:128]
    k_cvec<<<1, DIM, 0, stream>>>(posts, root, W2, cvec);
    k_gemm<true, true><<<512, 256, 0, stream>>>(conv1, W2 + DIM * DIM, cvec, h, N);
    k_agg<true><<<nblk, 256, 0, stream>>>(csr, rowptr, dinv, h, b2, root,
                                          conv1, meanacc, out, N);
    k_reduce<<<1, DIM, 0, stream>>>(meanacc, out, N);
}

// Round 11
// 332.353 us; speedup vs baseline: 4.6617x; 4.6617x over previous
//
#include <hip/hip_runtime.h>

#define DIM 128
typedef unsigned int uint;
typedef unsigned short ushort;

// bf16 pack (RNE)
__device__ __forceinline__ ushort f2bf(float x) {
    uint u = __float_as_uint(x);
    u = u + 0x7FFFu + ((u >> 16) & 1u);
    return (ushort)(u >> 16);
}
__device__ __forceinline__ uint pack2(float a, float b) {
    return (uint)f2bf(a) | ((uint)f2bf(b) << 16);
}

// ---------------- degree count ----------------
__global__ __launch_bounds__(256) void k_count(const int* __restrict__ dst,
                                               int* __restrict__ deg, int E) {
    int t = blockIdx.x * 256 + threadIdx.x;
    if (t < E) atomicAdd(&deg[dst[t]], 1);
}

__global__ __launch_bounds__(256) void k_dinv(const int* __restrict__ deg,
                                              float* __restrict__ dinv, int N) {
    int t = blockIdx.x * 256 + threadIdx.x;
    if (t < N) dinv[t] = rsqrtf((float)(deg[t] + 1));  // +1 = self-loop
}

// ---------------- parallel exclusive scan: blockwise -> seg -> add ----------------
__global__ __launch_bounds__(256) void k_scanA(const int* __restrict__ deg,
                                               int* __restrict__ rowptr,
                                               int* __restrict__ segsum, int N) {
    int i = blockIdx.x * 256 + threadIdx.x;
    int v = (i < N) ? deg[i] : 0;
    __shared__ int ps[256];
    ps[threadIdx.x] = v;
    __syncthreads();
    for (int off = 1; off < 256; off <<= 1) {
        int u = (threadIdx.x >= off) ? ps[threadIdx.x - off] : 0;
        __syncthreads();
        ps[threadIdx.x] += u;
        __syncthreads();
    }
    if (i < N) rowptr[i] = ps[threadIdx.x] - v;   // exclusive within block
    if (threadIdx.x == 255) segsum[blockIdx.x] = ps[255];
}

__global__ __launch_bounds__(256) void k_scanB(int* __restrict__ segsum, int nseg) {
    int t = threadIdx.x;
    int v = (t < nseg) ? segsum[t] : 0;
    __shared__ int ps[256];
    ps[t] = v;
    __syncthreads();
    for (int off = 1; off < 256; off <<= 1) {
        int u = (t >= off) ? ps[t - off] : 0;
        __syncthreads();
        ps[t] += u;
        __syncthreads();
    }
    if (t < nseg) segsum[t] = ps[t] - v;
}

__global__ __launch_bounds__(256) void k_scanC(int* __restrict__ rowptr,
                                               const int* __restrict__ segsum,
                                               int* __restrict__ cursor, int N, int E) {
    int i = blockIdx.x * 256 + threadIdx.x;
    if (i < N) {
        int r = rowptr[i] + segsum[blockIdx.x];
        rowptr[i] = r;
        cursor[i] = r;
    }
    if (i == 0) rowptr[N] = E;
}

// ---------------- CSR fill: {src, weight} per edge, grouped by dst ----------------
__global__ __launch_bounds__(256) void k_fill(const int* __restrict__ src,
                                              const int* __restrict__ dst,
                                              const float* __restrict__ dinv,
                                              int* __restrict__ cursor,
                                              int2* __restrict__ csr, int E) {
    int e = blockIdx.x * 256 + threadIdx.x;
    if (e >= E) return;
    int s = src[e], d = dst[e];
    int p = atomicAdd(&cursor[d], 1);
    float w = dinv[s] * dinv[d];
    csr[p] = make_int2(s, __float_as_int(w));
}

// ---------------- dense GEMM: H(bf16) = (cvec +) f(X) @ W ----------------
template<bool RELU_IN, bool ADD_C>
__global__ __launch_bounds__(256) void k_gemm(const float* __restrict__ X,
                                              const float* __restrict__ W,
                                              const float* __restrict__ Cvec,
                                              ushort* __restrict__ H, int n) {
    __shared__ float sW[64 * DIM];   // 32 KB, one K-chunk of W [k2][j]
    __shared__ float sX[32][DIM];    // 16 KB
    const int jq = threadIdx.x & 31;
    const int rr = threadIdx.x >> 5;   // 0..7
    float4 cj = ADD_C ? ((const float4*)Cvec)[jq] : make_float4(0.f, 0.f, 0.f, 0.f);
    for (int base = blockIdx.x * 32; base < n; base += gridDim.x * 32) {
        __syncthreads();
        for (int u = threadIdx.x; u < 32 * 32; u += 256) {
            int row = u >> 5, c4 = u & 31;
            int gi = base + row;
            float4 v = make_float4(0.f, 0.f, 0.f, 0.f);
            if (gi < n) v = ((const float4*)(X + (size_t)gi * DIM))[c4];
            if (RELU_IN) {
                v.x = fmaxf(v.x, 0.f); v.y = fmaxf(v.y, 0.f);
                v.z = fmaxf(v.z, 0.f); v.w = fmaxf(v.w, 0.f);
            }
            ((float4*)sX[row])[c4] = v;
        }
        float4 a0 = cj, a1 = cj, a2 = cj, a3 = cj;
        for (int kk = 0; kk < DIM; kk += 64) {
            __syncthreads();
            for (int u = threadIdx.x; u < 64 * 32; u += 256)
                ((float4*)sW)[u] = ((const float4*)(W + (size_t)kk * DIM))[u];
            __syncthreads();
            #pragma unroll 8
            for (int k2 = 0; k2 < 64; ++k2) {
                int k = kk + k2;
                float4 w4 = ((const float4*)sW)[k2 * 32 + jq];
                float x0 = sX[rr * 4 + 0][k], x1 = sX[rr * 4 + 1][k];
                float x2 = sX[rr * 4 + 2][k], x3 = sX[rr * 4 + 3][k];
                a0.x = fmaf(x0, w4.x, a0.x); a0.y = fmaf(x0, w4.y, a0.y);
                a0.z = fmaf(x0, w4.z, a0.z); a0.w = fmaf(x0, w4.w, a0.w);
                a1.x = fmaf(x1, w4.x, a1.x); a1.y = fmaf(x1, w4.y, a1.y);
                a1.z = fmaf(x1, w4.z, a1.z); a1.w = fmaf(x1, w4.w, a1.w);
                a2.x = fmaf(x2, w4.x, a2.x); a2.y = fmaf(x2, w4.y, a2.y);
                a2.z = fmaf(x2, w4.z, a2.z); a2.w = fmaf(x2, w4.w, a2.w);
                a3.x = fmaf(x3, w4.x, a3.x); a3.y = fmaf(x3, w4.y, a3.y);
                a3.z = fmaf(x3, w4.z, a3.z); a3.w = fmaf(x3, w4.w, a3.w);
            }
        }
        int i0 = base + rr * 4;
        if (i0 + 0 < n) ((uint2*)(H + (size_t)(i0 + 0) * DIM))[jq] =
            make_uint2(pack2(a0.x, a0.y), pack2(a0.z, a0.w));
        if (i0 + 1 < n) ((uint2*)(H + (size_t)(i0 + 1) * DIM))[jq] =
            make_uint2(pack2(a1.x, a1.y), pack2(a1.z, a1.w));
        if (i0 + 2 < n) ((uint2*)(H + (size_t)(i0 + 2) * DIM))[jq] =
            make_uint2(pack2(a2.x, a2.y), pack2(a2.z, a2.w));
        if (i0 + 3 < n) ((uint2*)(H + (size_t)(i0 + 3) * DIM))[jq] =
            make_uint2(pack2(a3.x, a3.y), pack2(a3.z, a3.w));
    }
}

// ---------------- c[j] = sum_k relu(posts[root][k]) * W2[k][j] ----------------
__global__ __launch_bounds__(DIM) void k_cvec(const float* __restrict__ posts,
                                              const int* __restrict__ root,
                                              const float* __restrict__ W2,
                                              float* __restrict__ cvec) {
    int j = threadIdx.x;
    const float* xr = posts + (size_t)root[0] * DIM;
    float acc = 0.0f;
    #pragma unroll 8
    for (int k = 0; k < DIM; ++k)
        acc = fmaf(fmaxf(xr[k], 0.0f), W2[k * DIM + j], acc);
    cvec[j] = acc;
}

// ---------------- wave-per-node 8-edge batch: scalar csr, pipelined row loads -----
// q = lane (0..63) owns dword q of the 256B bf16 row (2 bf16 -> accumulators a0,a1).
// All csr/rowptr indices pass through readfirstlane -> SGPR loads (lgkmcnt domain);
// the 8 row loads then have no vmcnt address dependency and issue back-to-back.
__device__ __forceinline__ void wave_accum(const int2* __restrict__ csr,
                                           int beg, int end, int q,
                                           const ushort* __restrict__ h,
                                           float& a0, float& a1) {
    int e = beg;
    for (; e + 8 <= end; e += 8) {
        int sc[8];
        float wt[8];
        #pragma unroll
        for (int u = 0; u < 8; ++u) {
            int2 c = csr[e + u];                       // uniform addr
            sc[u] = __builtin_amdgcn_readfirstlane(c.x);
            wt[u] = __int_as_float(__builtin_amdgcn_readfirstlane(c.y));
        }
        uint hv[8];
        #pragma unroll
        for (int u = 0; u < 8; ++u)
            hv[u] = ((const uint*)(h + (size_t)sc[u] * DIM))[q];  // SGPR base + lane off
        #pragma unroll
        for (int u = 0; u < 8; ++u) {
            a0 = fmaf(__uint_as_float(hv[u] << 16), wt[u], a0);
            a1 = fmaf(__uint_as_float(hv[u] & 0xFFFF0000u), wt[u], a1);
        }
    }
    int rem = end - e;
    if (rem > 0) {
        int sc[8];
        float wt[8];
        #pragma unroll
        for (int u = 0; u < 8; ++u) {
            int idx = e + u; idx = idx < end ? idx : end - 1;   // clamp (uniform)
            int2 c = csr[idx];
            sc[u] = __builtin_amdgcn_readfirstlane(c.x);
            wt[u] = (u < rem) ? __int_as_float(__builtin_amdgcn_readfirstlane(c.y)) : 0.f;
        }
        uint hv[8];
        #pragma unroll
        for (int u = 0; u < 8; ++u)
            hv[u] = ((const uint*)(h + (size_t)sc[u] * DIM))[q];
        #pragma unroll
        for (int u = 0; u < 8; ++u) {
            a0 = fmaf(__uint_as_float(hv[u] << 16), wt[u], a0);
            a1 = fmaf(__uint_as_float(hv[u] & 0xFFFF0000u), wt[u], a1);
        }
    }
}

// ---------------- gather layer 1: conv1(f32) = A_norm @ h + self + b1 ----------------
__global__ __launch_bounds__(256) void k_gather1(const int2* __restrict__ csr,
                                                 const int* __restrict__ rowptr,
                                                 const float* __restrict__ dinv,
                                                 const ushort* __restrict__ h,
                                                 const float* __restrict__ b1,
                                                 const int* __restrict__ root,
                                                 float* __restrict__ conv1,
                                                 float* __restrict__ out, int N) {
    int q = threadIdx.x & 63;
    int wid = blockIdx.x * 4 + (threadIdx.x >> 6);
    int wstride = gridDim.x * 4;
    float2 bv = ((const float2*)b1)[q];
    int rt = __builtin_amdgcn_readfirstlane(root[0]);
    for (int d = wid; d < N; d += wstride) {
        int beg = __builtin_amdgcn_readfirstlane(rowptr[d]);
        int end = __builtin_amdgcn_readfirstlane(rowptr[d + 1]);
        float a0 = 0.f, a1 = 0.f;
        wave_accum(csr, beg, end, q, h, a0, a1);
        float di = dinv[d], sl = di * di;
        uint hv = ((const uint*)(h + (size_t)d * DIM))[q];
        float2 r;
        r.x = fmaf(__uint_as_float(hv << 16), sl, a0) + bv.x;
        r.y = fmaf(__uint_as_float(hv & 0xFFFF0000u), sl, a1) + bv.y;
        ((float2*)(conv1 + (size_t)d * DIM))[q] = r;
        if (d == rt) ((float2*)out)[q] = r;   // conv1_root (no relu)
    }
}

// ---------------- gather layer 2 + relu + fused column-mean ----------------
__global__ __launch_bounds__(256) void k_gather2(const int2* __restrict__ csr,
                                                 const int* __restrict__ rowptr,
                                                 const float* __restrict__ dinv,
                                                 const ushort* __restrict__ h,
                                                 const float* __restrict__ b2,
                                                 float* __restrict__ meanacc, int N) {
    int q = threadIdx.x & 63;
    int wid = blockIdx.x * 4 + (threadIdx.x >> 6);
    int wstride = gridDim.x * 4;
    float2 bv = ((const float2*)b2)[q];
    float s0 = 0.f, s1 = 0.f;   // running column sums for cols 2q, 2q+1
    for (int d = wid; d < N; d += wstride) {
        int beg = __builtin_amdgcn_readfirstlane(rowptr[d]);
        int end = __builtin_amdgcn_readfirstlane(rowptr[d + 1]);
        float a0 = 0.f, a1 = 0.f;
        wave_accum(csr, beg, end, q, h, a0, a1);
        float di = dinv[d], sl = di * di;
        uint hv = ((const uint*)(h + (size_t)d * DIM))[q];
        s0 += fmaxf(fmaf(__uint_as_float(hv << 16), sl, a0) + bv.x, 0.f);
        s1 += fmaxf(fmaf(__uint_as_float(hv & 0xFFFF0000u), sl, a1) + bv.y, 0.f);
    }
    __shared__ float2 sp[256];
    sp[threadIdx.x] = make_float2(s0, s1);
    __syncthreads();
    if (threadIdx.x < 64) {
        float2 s = sp[threadIdx.x];
        #pragma unroll
        for (int g = 1; g < 4; ++g) {
            float2 o = sp[g * 64 + threadIdx.x];
            s.x += o.x; s.y += o.y;
        }
        unsafeAtomicAdd(&meanacc[q * 2 + 0], s.x);
        unsafeAtomicAdd(&meanacc[q * 2 + 1], s.y);
    }
}

__global__ __launch_bounds__(DIM) void k_reduce(const float* __restrict__ meanacc,
                                                float* __restrict__ out, int N) {
    int j = threadIdx.x;
    out[DIM + j] = meanacc[j] / (float)N;
}

extern "C" void kernel_launch(void* const* d_in, const int* in_sizes, int n_in,
                              void* d_out, int out_size, void* d_ws, size_t ws_size,
                              hipStream_t stream) {
    const float* posts = (const float*)d_in[0];
    const int*   eidx  = (const int*)d_in[1];
    const int*   root  = (const int*)d_in[2];
    const float* W1    = (const float*)d_in[3];
    const float* b1    = (const float*)d_in[4];
    const float* W2    = (const float*)d_in[5];
    const float* b2    = (const float*)d_in[6];
    float* out = (float*)d_out;

    int N = in_sizes[0] / DIM;
    int E = in_sizes[1] / 2;
    const int* src = eidx;
    const int* dst = eidx + E;
    int nseg = (N + 255) / 256;   // 196 for N=50000 (fits k_scanB's 256)

    char* ws = (char*)d_ws;
    size_t off = 0;
    auto alloc = [&](size_t bytes) {
        void* p = ws + off;
        off += (bytes + 511) & ~(size_t)511;
        return p;
    };
    int*    deg     = (int*)   alloc((size_t)N * 4);
    int*    rowptr  = (int*)   alloc((size_t)(N + 1) * 4);
    int*    cursor  = (int*)   alloc((size_t)N * 4);
    int*    segsum  = (int*)   alloc((size_t)nseg * 4);
    float*  dinv    = (float*) alloc((size_t)N * 4);
    float*  cvec    = (float*) alloc(DIM * 4);
    float*  meanacc = (float*) alloc(DIM * 4);
    int2*   csr     = (int2*)  alloc((size_t)E * 8);
    ushort* h       = (ushort*)alloc((size_t)N * DIM * 2);   // bf16 h1, then h2
    float*  conv1   = (float*) alloc((size_t)N * DIM * 4);   // conv1_out (f32)

    hipMemsetAsync(deg, 0, (size_t)N * 4, stream);
    hipMemsetAsync(meanacc, 0, DIM * 4, stream);

    // CSR build (once, shared by both layers); parallel 3-stage scan
    k_count<<<(E + 255) / 256, 256, 0, stream>>>(dst, deg, E);
    k_scanA<<<nseg, 256, 0, stream>>>(deg, rowptr, segsum, N);
    k_scanB<<<1, 256, 0, stream>>>(segsum, nseg);
    k_scanC<<<nseg, 256, 0, stream>>>(rowptr, segsum, cursor, N, E);
    k_dinv<<<(N + 255) / 256, 256, 0, stream>>>(deg, dinv, N);
    k_fill<<<(E + 255) / 256, 256, 0, stream>>>(src, dst, dinv, cursor, csr, E);

    // layer 1
    k_gemm<false, false><<<512, 256, 0, stream>>>(posts, W1, nullptr, h, N);
    k_gather1<<<2048, 256, 0, stream>>>(csr, rowptr, dinv, h, b1, root, conv1, out, N);

    // layer 2: h2 = cvec + relu(conv1) @ W2[128:], cvec = relu(post_root) @ W2[:128]
    k_cvec<<<1, DIM, 0, stream>>>(posts, root, W2, cvec);
    k_gemm<true, true><<<512, 256, 0, stream>>>(conv1, W2 + DIM * DIM, cvec, h, N);
    k_gather2<<<2048, 256, 0, stream>>>(csr, rowptr, dinv, h, b2, meanacc, N);
    k_reduce<<<1, DIM, 0, stream>>>(meanacc, out, N);
}